// Round 13
// baseline (371.242 us; speedup 1.0000x reference)
//
#include <hip/hip_runtime.h>

typedef unsigned short u16;
typedef unsigned int u32;
typedef __bf16 bfrag __attribute__((ext_vector_type(8)));
typedef float f32x4 __attribute__((ext_vector_type(4)));
typedef float f32x2 __attribute__((ext_vector_type(2)));

__device__ __forceinline__ u16 f2bf(float f) {
    u32 u = __float_as_uint(f);
    u32 r = (u + 0x7FFFu + ((u >> 16) & 1u)) >> 16;
    return (u16)r;
}
__device__ __forceinline__ float bf2f(u32 h) {
    return __uint_as_float(h << 16);
}

// ---------------- precompute: 4x weight prepack + message consts (one launch) ----------------
__global__ __launch_bounds__(256) void prepack_consts_kernel(
    const float* __restrict__ w11, const float* __restrict__ w12,
    const float* __restrict__ w21, const float* __restrict__ w22,
    u16* __restrict__ hi, u16* __restrict__ lo,
    const float* __restrict__ ne_b, const float* __restrict__ ee_w, const float* __restrict__ ee_b,
    const float* __restrict__ lin1_w, const float* __restrict__ lin1_b,
    const float* __restrict__ lin2_w, const float* __restrict__ lin2_b,
    float* __restrict__ u1, float* __restrict__ C1, float* __restrict__ u2, float* __restrict__ C2)
{
    if (blockIdx.x == 256) {
        int c = threadIdx.x;
        if (c < 128) {
            float s1 = 0.f, t1 = 0.f, s2 = 0.f, t2 = 0.f;
            for (int k = 0; k < 128; ++k) {
                float w1 = lin1_w[k * 128 + c];
                float w2 = lin2_w[k * 128 + c];
                float ew = ee_w[k], eb = ee_b[k];
                s1 = fmaf(ew, w1, s1); t1 = fmaf(eb, w1, t1);
                s2 = fmaf(ew, w2, s2); t2 = fmaf(eb, w2, t2);
            }
            u1[c] = s1; C1[c] = t1 + lin1_b[c] + ne_b[c];
            u2[c] = s2; C2[c] = t2 + lin2_b[c];
        }
        return;
    }
    int which = blockIdx.x >> 6;
    const float* w = (which == 0) ? w11 : (which == 1) ? w12 : (which == 2) ? w21 : w22;
    int o = (blockIdx.x & 63) * 256 + threadIdx.x;   // 0..16383
    int j = o & 7;
    int lane = (o >> 3) & 63;
    int ct = (o >> 9) & 7;
    int ks = o >> 12;
    int k = ks * 32 + ((lane >> 4) * 8) + j;
    int c = ct * 16 + (lane & 15);
    float v = w[k * 128 + c];
    u16 h = f2bf(v);
    float vh = bf2f(h);
    u16 l = f2bf(v - vh);
    hi[which * 16384 + o] = h;
    lo[which * 16384 + o] = l;
}

// ---------------- bucket edge count + inline exclusive scan (ticket) ----------------
__global__ __launch_bounds__(1024) void bcount_kernel(
    const int* __restrict__ dst, int* __restrict__ bcnt, int* __restrict__ done,
    int* __restrict__ bstart, int* __restrict__ bcur, int E, int nb)
{
    __shared__ int h[256];
    __shared__ int is_last;
    if (threadIdx.x < 256) h[threadIdx.x] = 0;
    __syncthreads();
    int idx = blockIdx.x * 1024 + threadIdx.x;   // int4 index, covers 4 edges
    int e = idx * 4;
    if (e + 3 < E) {
        int4 d4 = ((const int4*)dst)[idx];
        atomicAdd(&h[d4.x >> 9], 1);
        atomicAdd(&h[d4.y >> 9], 1);
        atomicAdd(&h[d4.z >> 9], 1);
        atomicAdd(&h[d4.w >> 9], 1);
    } else {
        for (int k = e; k < E; ++k) atomicAdd(&h[dst[k] >> 9], 1);
    }
    __syncthreads();
    if (threadIdx.x < 256 && h[threadIdx.x]) atomicAdd(&bcnt[threadIdx.x], h[threadIdx.x]);
    __syncthreads();
    if (threadIdx.x == 0) {
        __threadfence();
        is_last = (atomicAdd(done, 1) == (int)gridDim.x - 1);
    }
    __syncthreads();
    if (!is_last) return;
    if (threadIdx.x < 256) h[threadIdx.x] = atomicAdd(&bcnt[threadIdx.x], 0);
    __syncthreads();
    __shared__ int excl[256];
    if (threadIdx.x < 64) {
        int l = threadIdx.x;
        int v0 = h[4 * l], v1 = h[4 * l + 1], v2 = h[4 * l + 2], v3 = h[4 * l + 3];
        int tot = v0 + v1 + v2 + v3;
        int run = tot;
#pragma unroll
        for (int off = 1; off < 64; off <<= 1) {
            int t = __shfl_up(run, off);
            if (l >= off) run += t;
        }
        int ex = run - tot;
        excl[4 * l] = ex;
        excl[4 * l + 1] = ex + v0;
        excl[4 * l + 2] = ex + v0 + v1;
        excl[4 * l + 3] = ex + v0 + v1 + v2;
    }
    __syncthreads();
    if (threadIdx.x < nb) {
        int ex = excl[threadIdx.x];
        bstart[threadIdx.x] = ex;
        bcur[threadIdx.x] = ex;
        if (threadIdx.x == nb - 1) bstart[nb] = ex + h[threadIdx.x];
    }
}

// block-local counting sort by bucket, coalesced run flush.
// record: x = src | (dst&511)<<17 (src < 2^17), y = attr bits
__global__ __launch_bounds__(1024) void bin_kernel(
    const int* __restrict__ src, const int* __restrict__ dst, const float* __restrict__ eattr,
    int* __restrict__ bucket_cursor,
    int2* __restrict__ binned, int E, int nb)
{
    __shared__ int hist[256];
    __shared__ int basel[256];
    __shared__ int gbase[256];
    __shared__ int2 stage[4096];
    __shared__ unsigned char sb[4096];
    const int tid = threadIdx.x;
    const int e0 = blockIdx.x * 4096;
    const int valid = min(4096, E - e0);

    if (tid < 256) hist[tid] = 0;
    __syncthreads();

    int d[4], s[4], a[4], rk[4];
    bool ok[4];
#pragma unroll
    for (int k = 0; k < 4; ++k) {
        int e = e0 + k * 1024 + tid;
        ok[k] = e < E;
        if (ok[k]) {
            d[k] = dst[e];
            s[k] = src[e];
            a[k] = __float_as_int(eattr[e]);
        }
    }
#pragma unroll
    for (int k = 0; k < 4; ++k) {
        if (ok[k]) rk[k] = atomicAdd(&hist[d[k] >> 9], 1);
    }
    __syncthreads();
    if (tid < 64) {
        int l = tid;
        int v0 = hist[4 * l], v1 = hist[4 * l + 1], v2 = hist[4 * l + 2], v3 = hist[4 * l + 3];
        int tot = v0 + v1 + v2 + v3;
        int run = tot;
#pragma unroll
        for (int off = 1; off < 64; off <<= 1) {
            int t = __shfl_up(run, off);
            if (l >= off) run += t;
        }
        int ex = run - tot;
        basel[4 * l] = ex;
        basel[4 * l + 1] = ex + v0;
        basel[4 * l + 2] = ex + v0 + v1;
        basel[4 * l + 3] = ex + v0 + v1 + v2;
    }
    __syncthreads();
    if (tid < nb && hist[tid] > 0) gbase[tid] = atomicAdd(&bucket_cursor[tid], hist[tid]);
#pragma unroll
    for (int k = 0; k < 4; ++k) {
        if (ok[k]) {
            int b = d[k] >> 9;
            int pos = basel[b] + rk[k];
            stage[pos] = make_int2(s[k] | ((d[k] & 511) << 17), a[k]);
            sb[pos] = (unsigned char)b;
        }
    }
    __syncthreads();
    for (int i = tid; i < valid; i += 1024) {
        int b = (int)sb[i];
        binned[gbase[b] + (i - basel[b])] = stage[i];
    }
}

// One block per bucket: LDS histogram by dlo -> rowptr slice -> cursor scatter
__global__ __launch_bounds__(1024) void fine_kernel(
    const int2* __restrict__ binned, const int* __restrict__ bstart,
    int* __restrict__ rowptr, int2* __restrict__ edges, int N, int nbuckets)
{
    __shared__ int hist[512];
    __shared__ int excl[512];
    const int tid = threadIdx.x;
    const int b = blockIdx.x;
    const int s0 = bstart[b], s1 = bstart[b + 1];
    if (tid < 512) hist[tid] = 0;
    __syncthreads();
    for (int i = s0 + tid; i < s1; i += 1024)
        atomicAdd(&hist[(binned[i].x >> 17) & 511], 1);
    __syncthreads();
    if (tid < 64) {
        int l = tid;
        int v[8], pre[8];
        int tot = 0;
#pragma unroll
        for (int k = 0; k < 8; ++k) { v[k] = hist[8 * l + k]; pre[k] = tot; tot += v[k]; }
        int run = tot;
#pragma unroll
        for (int off = 1; off < 64; off <<= 1) {
            int t = __shfl_up(run, off);
            if (l >= off) run += t;
        }
        int ex = run - tot;
#pragma unroll
        for (int k = 0; k < 8; ++k) excl[8 * l + k] = ex + pre[k];
    }
    __syncthreads();
    const int nbase = b << 9;
    if (tid < 512 && nbase + tid < N) rowptr[nbase + tid] = s0 + excl[tid];
    if (b == nbuckets - 1 && tid == 0) rowptr[N] = s1;
    __syncthreads();
    for (int i = s0 + tid; i < s1; i += 1024) {
        int2 ed = binned[i];
        int dlo = (ed.x >> 17) & 511;
        ed.x &= 0x1FFFF;
        int pos = atomicAdd(&excl[dlo], 1);
        edges[s0 + pos] = ed;
    }
}

// ---------------- pull aggregation (scalarized meta + packed f32x2 math) ----------------

__global__ __launch_bounds__(256) void pull1_kernel(
    const float* __restrict__ x,
    const int* __restrict__ rowptr, const int2* __restrict__ edges,
    const float* __restrict__ ne_w, const float* __restrict__ ne_b,
    const float* __restrict__ u1, const float* __restrict__ C1,
    u16* __restrict__ zb, int N)
{
    int lane = threadIdx.x & 63;
    int node = blockIdx.x * 4 + (threadIdx.x >> 6);
    if (node >= N) return;
    f32x2 A  = *(const f32x2*)(ne_w + 2 * lane);
    f32x2 Bv = *(const f32x2*)(u1   + 2 * lane);
    f32x2 Cv = *(const f32x2*)(C1   + 2 * lane);
    f32x2 nb = *(const f32x2*)(ne_b + 2 * lane);
    const f32x2 zero = {0.f, 0.f};
    int jb = rowptr[node], je = rowptr[node + 1];
    f32x2 acc = zero;
    int j = jb;
    for (; j + 8 <= je; j += 8) {
        float xs[8], av[8];
#pragma unroll
        for (int t = 0; t < 8; ++t) {
            int2 ep = edges[j + t];
            int s = __builtin_amdgcn_readfirstlane(ep.x);
            av[t] = __int_as_float(__builtin_amdgcn_readfirstlane(ep.y));
            xs[t] = x[s];
        }
#pragma unroll
        for (int t = 0; t < 8; ++t) {
            f32x2 m = __builtin_elementwise_fma((f32x2){xs[t], xs[t]}, A,
                        __builtin_elementwise_fma((f32x2){av[t], av[t]}, Bv, Cv));
            acc += __builtin_elementwise_max(m, zero);
        }
    }
    for (; j < je; ++j) {
        int2 ep = edges[j];
        int s = __builtin_amdgcn_readfirstlane(ep.x);
        float av = __int_as_float(__builtin_amdgcn_readfirstlane(ep.y));
        float xs = x[s];
        f32x2 m = __builtin_elementwise_fma((f32x2){xs, xs}, A,
                    __builtin_elementwise_fma((f32x2){av, av}, Bv, Cv));
        acc += __builtin_elementwise_max(m, zero);
    }
    float xn = x[node];
    f32x2 z = __builtin_elementwise_fma((f32x2){xn, xn}, A, nb) + acc;
    ((u32*)(zb + (long)node * 128))[lane] = (u32)f2bf(z.x) | ((u32)f2bf(z.y) << 16);
}

// pull2: TWO nodes per wave, interleaved 8-deep batches -> 16 row-loads in flight.
__global__ __launch_bounds__(256) void pull2_kernel(
    const u16* __restrict__ h1b,
    const int* __restrict__ rowptr, const int2* __restrict__ edges,
    const float* __restrict__ u2, const float* __restrict__ C2,
    u16* __restrict__ zb2, int N)
{
    int lane = threadIdx.x & 63;
    int w = threadIdx.x >> 6;
    int n0 = blockIdx.x * 8 + w * 2;
    if (n0 >= N) return;
    int n1 = n0 + 1;
    bool has1 = n1 < N;
    f32x2 Bv = *(const f32x2*)(u2 + 2 * lane);
    f32x2 Cv = *(const f32x2*)(C2 + 2 * lane);
    const f32x2 zero = {0.f, 0.f};
    int jb0 = rowptr[n0], je0 = rowptr[n0 + 1];
    int jb1 = has1 ? rowptr[n1] : 0;
    int je1 = has1 ? rowptr[n1 + 1] : 0;
    f32x2 acc0 = zero, acc1 = zero;
    int j0 = jb0, j1 = jb1;

    // interleaved main loop: 16 independent row loads in flight
    while (j0 + 8 <= je0 && j1 + 8 <= je1) {
        int s0[8], s1[8];
        float a0[8], a1[8];
        u32 h0[8], h1v[8];
#pragma unroll
        for (int t = 0; t < 8; ++t) {
            int2 ep = edges[j0 + t];
            s0[t] = __builtin_amdgcn_readfirstlane(ep.x);
            a0[t] = __int_as_float(__builtin_amdgcn_readfirstlane(ep.y));
        }
#pragma unroll
        for (int t = 0; t < 8; ++t) {
            int2 ep = edges[j1 + t];
            s1[t] = __builtin_amdgcn_readfirstlane(ep.x);
            a1[t] = __int_as_float(__builtin_amdgcn_readfirstlane(ep.y));
        }
#pragma unroll
        for (int t = 0; t < 8; ++t)
            h0[t] = *(const u32*)(h1b + (long)s0[t] * 128 + 2 * lane);
#pragma unroll
        for (int t = 0; t < 8; ++t)
            h1v[t] = *(const u32*)(h1b + (long)s1[t] * 128 + 2 * lane);
#pragma unroll
        for (int t = 0; t < 8; ++t) {
            f32x2 h = { __uint_as_float(h0[t] << 16), __uint_as_float(h0[t] & 0xFFFF0000u) };
            f32x2 m = h + __builtin_elementwise_fma((f32x2){a0[t], a0[t]}, Bv, Cv);
            acc0 += __builtin_elementwise_max(m, zero);
        }
#pragma unroll
        for (int t = 0; t < 8; ++t) {
            f32x2 h = { __uint_as_float(h1v[t] << 16), __uint_as_float(h1v[t] & 0xFFFF0000u) };
            f32x2 m = h + __builtin_elementwise_fma((f32x2){a1[t], a1[t]}, Bv, Cv);
            acc1 += __builtin_elementwise_max(m, zero);
        }
        j0 += 8;
        j1 += 8;
    }
    // drain node0
    for (; j0 + 8 <= je0; j0 += 8) {
        int sidx[8]; float av[8]; u32 hv[8];
#pragma unroll
        for (int t = 0; t < 8; ++t) {
            int2 ep = edges[j0 + t];
            sidx[t] = __builtin_amdgcn_readfirstlane(ep.x);
            av[t] = __int_as_float(__builtin_amdgcn_readfirstlane(ep.y));
        }
#pragma unroll
        for (int t = 0; t < 8; ++t)
            hv[t] = *(const u32*)(h1b + (long)sidx[t] * 128 + 2 * lane);
#pragma unroll
        for (int t = 0; t < 8; ++t) {
            f32x2 h = { __uint_as_float(hv[t] << 16), __uint_as_float(hv[t] & 0xFFFF0000u) };
            f32x2 m = h + __builtin_elementwise_fma((f32x2){av[t], av[t]}, Bv, Cv);
            acc0 += __builtin_elementwise_max(m, zero);
        }
    }
    for (; j0 < je0; ++j0) {
        int2 ep = edges[j0];
        int s = __builtin_amdgcn_readfirstlane(ep.x);
        float av = __int_as_float(__builtin_amdgcn_readfirstlane(ep.y));
        u32 hv = *(const u32*)(h1b + (long)s * 128 + 2 * lane);
        f32x2 h = { __uint_as_float(hv << 16), __uint_as_float(hv & 0xFFFF0000u) };
        f32x2 m = h + __builtin_elementwise_fma((f32x2){av, av}, Bv, Cv);
        acc0 += __builtin_elementwise_max(m, zero);
    }
    // drain node1
    for (; j1 + 8 <= je1; j1 += 8) {
        int sidx[8]; float av[8]; u32 hv[8];
#pragma unroll
        for (int t = 0; t < 8; ++t) {
            int2 ep = edges[j1 + t];
            sidx[t] = __builtin_amdgcn_readfirstlane(ep.x);
            av[t] = __int_as_float(__builtin_amdgcn_readfirstlane(ep.y));
        }
#pragma unroll
        for (int t = 0; t < 8; ++t)
            hv[t] = *(const u32*)(h1b + (long)sidx[t] * 128 + 2 * lane);
#pragma unroll
        for (int t = 0; t < 8; ++t) {
            f32x2 h = { __uint_as_float(hv[t] << 16), __uint_as_float(hv[t] & 0xFFFF0000u) };
            f32x2 m = h + __builtin_elementwise_fma((f32x2){av[t], av[t]}, Bv, Cv);
            acc1 += __builtin_elementwise_max(m, zero);
        }
    }
    for (; j1 < je1; ++j1) {
        int2 ep = edges[j1];
        int s = __builtin_amdgcn_readfirstlane(ep.x);
        float av = __int_as_float(__builtin_amdgcn_readfirstlane(ep.y));
        u32 hv = *(const u32*)(h1b + (long)s * 128 + 2 * lane);
        f32x2 h = { __uint_as_float(hv << 16), __uint_as_float(hv & 0xFFFF0000u) };
        f32x2 m = h + __builtin_elementwise_fma((f32x2){av, av}, Bv, Cv);
        acc1 += __builtin_elementwise_max(m, zero);
    }
    // epilogue
    {
        u32 hn = *(const u32*)(h1b + (long)n0 * 128 + 2 * lane);
        f32x2 hnv = { __uint_as_float(hn << 16), __uint_as_float(hn & 0xFFFF0000u) };
        f32x2 z = hnv + acc0;
        ((u32*)(zb2 + (long)n0 * 128))[lane] = (u32)f2bf(z.x) | ((u32)f2bf(z.y) << 16);
    }
    if (has1) {
        u32 hn = *(const u32*)(h1b + (long)n1 * 128 + 2 * lane);
        f32x2 hnv = { __uint_as_float(hn << 16), __uint_as_float(hn & 0xFFFF0000u) };
        f32x2 z = hnv + acc1;
        ((u32*)(zb2 + (long)n1 * 128))[lane] = (u32)f2bf(z.x) | ((u32)f2bf(z.y) << 16);
    }
}

// ---------------- fused 2-GEMM node MLP (bf16 MFMA, split weights) ----------------
__global__ __launch_bounds__(256) void mlp_kernel(
    const u16* __restrict__ zb,
    const u16* __restrict__ w1hi, const u16* __restrict__ w1lo,
    const u16* __restrict__ w2hi, const u16* __restrict__ w2lo,
    const float* __restrict__ b1, const float* __restrict__ b2,
    u16* __restrict__ outb)
{
    __shared__ __align__(16) u16 tls[64][136];
    const int lane = threadIdx.x & 63;
    const int wv = threadIdx.x >> 6;
    const int m = lane & 15;
    const int q = lane >> 4;
    const int ko = q * 8;
    const long tile_row = (long)blockIdx.x * 64 + wv * 16;

    f32x4 acc[8];
#pragma unroll
    for (int ct = 0; ct < 8; ++ct) acc[ct] = (f32x4){0.f, 0.f, 0.f, 0.f};

#pragma unroll
    for (int ks = 0; ks < 4; ++ks) {
        bfrag a = *(const bfrag*)(zb + (tile_row + m) * 128 + ks * 32 + ko);
#pragma unroll
        for (int ct = 0; ct < 8; ++ct) {
            const int off = (((ks * 8 + ct) * 64) + lane) * 8;
            bfrag bh = *(const bfrag*)(w1hi + off);
            bfrag bl = *(const bfrag*)(w1lo + off);
            acc[ct] = __builtin_amdgcn_mfma_f32_16x16x32_bf16(a, bh, acc[ct], 0, 0, 0);
            acc[ct] = __builtin_amdgcn_mfma_f32_16x16x32_bf16(a, bl, acc[ct], 0, 0, 0);
        }
    }
#pragma unroll
    for (int ct = 0; ct < 8; ++ct) {
        float bv = b1[ct * 16 + m];
#pragma unroll
        for (int r = 0; r < 4; ++r) {
            float v = fmaxf(acc[ct][r] + bv, 0.f);
            tls[wv * 16 + q * 4 + r][ct * 16 + m] = f2bf(v);
        }
    }
    __syncthreads();

    f32x4 acc2[8];
#pragma unroll
    for (int ct = 0; ct < 8; ++ct) acc2[ct] = (f32x4){0.f, 0.f, 0.f, 0.f};

#pragma unroll
    for (int ks = 0; ks < 4; ++ks) {
        bfrag a = *(const bfrag*)(&tls[wv * 16 + m][ks * 32 + ko]);
#pragma unroll
        for (int ct = 0; ct < 8; ++ct) {
            const int off = (((ks * 8 + ct) * 64) + lane) * 8;
            bfrag bh = *(const bfrag*)(w2hi + off);
            bfrag bl = *(const bfrag*)(w2lo + off);
            acc2[ct] = __builtin_amdgcn_mfma_f32_16x16x32_bf16(a, bh, acc2[ct], 0, 0, 0);
            acc2[ct] = __builtin_amdgcn_mfma_f32_16x16x32_bf16(a, bl, acc2[ct], 0, 0, 0);
        }
    }
    __syncthreads();
#pragma unroll
    for (int ct = 0; ct < 8; ++ct) {
        float bv = b2[ct * 16 + m];
#pragma unroll
        for (int r = 0; r < 4; ++r) {
            float v = fmaxf(acc2[ct][r] + bv, 0.f);
            tls[wv * 16 + q * 4 + r][ct * 16 + m] = f2bf(v);
        }
    }
    __syncthreads();
    const long base_row = (long)blockIdx.x * 64;
#pragma unroll
    for (int it = 0; it < 4; ++it) {
        int chunk = threadIdx.x + it * 256;   // 0..1023
        int row = chunk >> 4;
        int c8 = (chunk & 15) * 8;
        *(uint4*)(outb + (base_row + row) * 128 + c8) = *(const uint4*)(&tls[row][c8]);
    }
}

// Same MLP but final layer: no h2 global write — pool directly from LDS.
__global__ __launch_bounds__(256) void mlp_pool_kernel(
    const u16* __restrict__ zb,
    const u16* __restrict__ w1hi, const u16* __restrict__ w1lo,
    const u16* __restrict__ w2hi, const u16* __restrict__ w2lo,
    const float* __restrict__ b1, const float* __restrict__ b2,
    const int* __restrict__ batch, float* __restrict__ poolacc, int N)
{
    __shared__ __align__(16) u16 tls[64][136];
    __shared__ int bsh[64];
    const int lane = threadIdx.x & 63;
    const int wv = threadIdx.x >> 6;
    const int m = lane & 15;
    const int q = lane >> 4;
    const int ko = q * 8;
    const long tile_row = (long)blockIdx.x * 64 + wv * 16;
    const long base_row = (long)blockIdx.x * 64;

    if (threadIdx.x < 64) {
        long node = base_row + threadIdx.x;
        bsh[threadIdx.x] = (node < N) ? batch[node] : -1;
    }

    f32x4 acc[8];
#pragma unroll
    for (int ct = 0; ct < 8; ++ct) acc[ct] = (f32x4){0.f, 0.f, 0.f, 0.f};

#pragma unroll
    for (int ks = 0; ks < 4; ++ks) {
        bfrag a = *(const bfrag*)(zb + (tile_row + m) * 128 + ks * 32 + ko);
#pragma unroll
        for (int ct = 0; ct < 8; ++ct) {
            const int off = (((ks * 8 + ct) * 64) + lane) * 8;
            bfrag bh = *(const bfrag*)(w1hi + off);
            bfrag bl = *(const bfrag*)(w1lo + off);
            acc[ct] = __builtin_amdgcn_mfma_f32_16x16x32_bf16(a, bh, acc[ct], 0, 0, 0);
            acc[ct] = __builtin_amdgcn_mfma_f32_16x16x32_bf16(a, bl, acc[ct], 0, 0, 0);
        }
    }
#pragma unroll
    for (int ct = 0; ct < 8; ++ct) {
        float bv = b1[ct * 16 + m];
#pragma unroll
        for (int r = 0; r < 4; ++r) {
            float v = fmaxf(acc[ct][r] + bv, 0.f);
            tls[wv * 16 + q * 4 + r][ct * 16 + m] = f2bf(v);
        }
    }
    __syncthreads();

    f32x4 acc2[8];
#pragma unroll
    for (int ct = 0; ct < 8; ++ct) acc2[ct] = (f32x4){0.f, 0.f, 0.f, 0.f};

#pragma unroll
    for (int ks = 0; ks < 4; ++ks) {
        bfrag a = *(const bfrag*)(&tls[wv * 16 + m][ks * 32 + ko]);
#pragma unroll
        for (int ct = 0; ct < 8; ++ct) {
            const int off = (((ks * 8 + ct) * 64) + lane) * 8;
            bfrag bh = *(const bfrag*)(w2hi + off);
            bfrag bl = *(const bfrag*)(w2lo + off);
            acc2[ct] = __builtin_amdgcn_mfma_f32_16x16x32_bf16(a, bh, acc2[ct], 0, 0, 0);
            acc2[ct] = __builtin_amdgcn_mfma_f32_16x16x32_bf16(a, bl, acc2[ct], 0, 0, 0);
        }
    }
    __syncthreads();   // tls reuse
#pragma unroll
    for (int ct = 0; ct < 8; ++ct) {
        float bv = b2[ct * 16 + m];
#pragma unroll
        for (int r = 0; r < 4; ++r) {
            float v = fmaxf(acc2[ct][r] + bv, 0.f);
            tls[wv * 16 + q * 4 + r][ct * 16 + m] = f2bf(v);
        }
    }
    __syncthreads();

    int c = threadIdx.x & 127;
    int half = threadIdx.x >> 7;
    int r0 = half * 32, r1 = r0 + 32;
    int cur = -1;
    float sum = 0.f;
    for (int r = r0; r < r1; ++r) {
        int g = bsh[r];
        if (g < 0) break;
        float v = bf2f((u32)tls[r][c]);
        if (g != cur) {
            if (cur >= 0) atomicAdd(&poolacc[cur * 128 + c], sum);
            sum = 0.f;
            cur = g;
        }
        sum += v;
    }
    if (cur >= 0) atomicAdd(&poolacc[cur * 128 + c], sum);
}

// divide by per-graph counts (binary search in sorted batch)
__global__ __launch_bounds__(128) void pool2_kernel(
    const float* __restrict__ acc, const int* __restrict__ batch,
    float* __restrict__ out, int n)
{
    int g = blockIdx.x;
    int c = threadIdx.x;
    int lo = 0, hi = n;
    while (lo < hi) { int mid = (lo + hi) >> 1; if (batch[mid] < g) lo = mid + 1; else hi = mid; }
    int s = lo;
    lo = s; hi = n;
    while (lo < hi) { int mid = (lo + hi) >> 1; if (batch[mid] < g + 1) lo = mid + 1; else hi = mid; }
    int cnt = lo - s;
    out[g * 128 + c] = acc[g * 128 + c] / (float)(cnt > 0 ? cnt : 1);
}

// ---------------- launch ----------------
extern "C" void kernel_launch(void* const* d_in, const int* in_sizes, int n_in,
                              void* d_out, int out_size, void* d_ws, size_t ws_size,
                              hipStream_t stream)
{
    const float* x      = (const float*)d_in[0];
    const int*   ei     = (const int*)d_in[1];
    const float* eattr  = (const float*)d_in[2];
    const int*   batch  = (const int*)d_in[3];
    const float* ne_w   = (const float*)d_in[4];
    const float* ne_b   = (const float*)d_in[5];
    const float* ee_w   = (const float*)d_in[6];
    const float* ee_b   = (const float*)d_in[7];
    const float* lin1_w = (const float*)d_in[8];
    const float* lin1_b = (const float*)d_in[9];
    const float* w11    = (const float*)d_in[10];
    const float* b11    = (const float*)d_in[11];
    const float* w12    = (const float*)d_in[12];
    const float* b12    = (const float*)d_in[13];
    const float* lin2_w = (const float*)d_in[14];
    const float* lin2_b = (const float*)d_in[15];
    const float* w21    = (const float*)d_in[16];
    const float* b21    = (const float*)d_in[17];
    const float* w22    = (const float*)d_in[18];
    const float* b22    = (const float*)d_in[19];

    const int N = in_sizes[0];
    const int E = in_sizes[2];
    const int G = out_size / 128;
    const int Npad = ((N + 63) / 64) * 64;
    const int nb = (N + 511) >> 9;     // 512-node buckets (<=256)
    const int* esrc = ei;
    const int* edst = ei + E;

    char* p = (char*)d_ws;
    auto alloc = [&](size_t bytes) -> void* {
        void* r = (void*)p;
        p += (bytes + 255) & ~(size_t)255;
        return r;
    };
    float* u1 = (float*)alloc(128 * 4);
    float* C1 = (float*)alloc(128 * 4);
    float* u2 = (float*)alloc(128 * 4);
    float* C2 = (float*)alloc(128 * 4);
    int* bcnt   = (int*)alloc(1024);
    int* done   = (int*)alloc(256);
    float* poolacc = (float*)alloc((size_t)G * 128 * 4);
    int* bstart = (int*)alloc(((size_t)nb + 1) * 4);
    int* bcur   = (int*)alloc((size_t)nb * 4);
    int* rowptr = (int*)alloc(((size_t)N + 1) * 4);
    int2* edges = (int2*)alloc((size_t)E * 8);
    int2* binned = (int2*)alloc((size_t)E * 8);
    u16* whi = (u16*)alloc((size_t)4 * 16384 * 2);
    u16* wlo = (u16*)alloc((size_t)4 * 16384 * 2);
    u16* bufA = (u16*)alloc((size_t)Npad * 128 * 2);
    u16* bufB = (u16*)alloc((size_t)Npad * 128 * 2);

    // one memset covers bcnt..done..poolacc (adjacent allocations)
    size_t zbytes = (size_t)((char*)poolacc + (size_t)G * 128 * 4 - (char*)bcnt);
    hipMemsetAsync(bcnt, 0, zbytes, stream);

    prepack_consts_kernel<<<257, 256, 0, stream>>>(
        w11, w12, w21, w22, whi, wlo,
        ne_b, ee_w, ee_b, lin1_w, lin1_b, lin2_w, lin2_b, u1, C1, u2, C2);

    bcount_kernel<<<(E + 4095) / 4096, 1024, 0, stream>>>(edst, bcnt, done, bstart, bcur, E, nb);
    bin_kernel<<<(E + 4095) / 4096, 1024, 0, stream>>>(esrc, edst, eattr, bcur, binned, E, nb);
    fine_kernel<<<nb, 1024, 0, stream>>>(binned, bstart, rowptr, edges, N, nb);

    pull1_kernel<<<(N + 3) / 4, 256, 0, stream>>>(x, rowptr, edges, ne_w, ne_b, u1, C1,
                                                  bufA, N);
    mlp_kernel<<<Npad / 64, 256, 0, stream>>>(bufA, whi, wlo, whi + 16384, wlo + 16384,
                                              b11, b12, bufB);
    pull2_kernel<<<(N + 7) / 8, 256, 0, stream>>>(bufB, rowptr, edges, u2, C2, bufA, N);
    mlp_pool_kernel<<<Npad / 64, 256, 0, stream>>>(bufA, whi + 32768, wlo + 32768,
                                                   whi + 49152, wlo + 49152, b21, b22,
                                                   batch, poolacc, N);

    pool2_kernel<<<G, 128, 0, stream>>>(poolacc, batch, (float*)d_out, N);
}

// Round 14
// 361.613 us; speedup vs baseline: 1.0266x; 1.0266x over previous
//
#include <hip/hip_runtime.h>

typedef unsigned short u16;
typedef unsigned int u32;
typedef __bf16 bfrag __attribute__((ext_vector_type(8)));
typedef float f32x4 __attribute__((ext_vector_type(4)));
typedef float f32x2 __attribute__((ext_vector_type(2)));

__device__ __forceinline__ u16 f2bf(float f) {
    u32 u = __float_as_uint(f);
    u32 r = (u + 0x7FFFu + ((u >> 16) & 1u)) >> 16;
    return (u16)r;
}
__device__ __forceinline__ float bf2f(u32 h) {
    return __uint_as_float(h << 16);
}

// ---------------- precompute: 4x weight prepack + message consts (one launch) ----------------
__global__ __launch_bounds__(256) void prepack_consts_kernel(
    const float* __restrict__ w11, const float* __restrict__ w12,
    const float* __restrict__ w21, const float* __restrict__ w22,
    u16* __restrict__ hi, u16* __restrict__ lo,
    const float* __restrict__ ne_b, const float* __restrict__ ee_w, const float* __restrict__ ee_b,
    const float* __restrict__ lin1_w, const float* __restrict__ lin1_b,
    const float* __restrict__ lin2_w, const float* __restrict__ lin2_b,
    float* __restrict__ u1, float* __restrict__ C1, float* __restrict__ u2, float* __restrict__ C2)
{
    if (blockIdx.x == 256) {
        int c = threadIdx.x;
        if (c < 128) {
            float s1 = 0.f, t1 = 0.f, s2 = 0.f, t2 = 0.f;
            for (int k = 0; k < 128; ++k) {
                float w1 = lin1_w[k * 128 + c];
                float w2 = lin2_w[k * 128 + c];
                float ew = ee_w[k], eb = ee_b[k];
                s1 = fmaf(ew, w1, s1); t1 = fmaf(eb, w1, t1);
                s2 = fmaf(ew, w2, s2); t2 = fmaf(eb, w2, t2);
            }
            u1[c] = s1; C1[c] = t1 + lin1_b[c] + ne_b[c];
            u2[c] = s2; C2[c] = t2 + lin2_b[c];
        }
        return;
    }
    int which = blockIdx.x >> 6;
    const float* w = (which == 0) ? w11 : (which == 1) ? w12 : (which == 2) ? w21 : w22;
    int o = (blockIdx.x & 63) * 256 + threadIdx.x;   // 0..16383
    int j = o & 7;
    int lane = (o >> 3) & 63;
    int ct = (o >> 9) & 7;
    int ks = o >> 12;
    int k = ks * 32 + ((lane >> 4) * 8) + j;
    int c = ct * 16 + (lane & 15);
    float v = w[k * 128 + c];
    u16 h = f2bf(v);
    float vh = bf2f(h);
    u16 l = f2bf(v - vh);
    hi[which * 16384 + o] = h;
    lo[which * 16384 + o] = l;
}

// ---------------- bucket edge count + inline exclusive scan (ticket) ----------------
__global__ __launch_bounds__(1024) void bcount_kernel(
    const int* __restrict__ dst, int* __restrict__ bcnt, int* __restrict__ done,
    int* __restrict__ bstart, int* __restrict__ bcur, int E, int nb)
{
    __shared__ int h[256];
    __shared__ int is_last;
    if (threadIdx.x < 256) h[threadIdx.x] = 0;
    __syncthreads();
    int idx = blockIdx.x * 1024 + threadIdx.x;   // int4 index, covers 4 edges
    int e = idx * 4;
    if (e + 3 < E) {
        int4 d4 = ((const int4*)dst)[idx];
        atomicAdd(&h[d4.x >> 9], 1);
        atomicAdd(&h[d4.y >> 9], 1);
        atomicAdd(&h[d4.z >> 9], 1);
        atomicAdd(&h[d4.w >> 9], 1);
    } else {
        for (int k = e; k < E; ++k) atomicAdd(&h[dst[k] >> 9], 1);
    }
    __syncthreads();
    if (threadIdx.x < 256 && h[threadIdx.x]) atomicAdd(&bcnt[threadIdx.x], h[threadIdx.x]);
    __syncthreads();
    if (threadIdx.x == 0) {
        __threadfence();
        is_last = (atomicAdd(done, 1) == (int)gridDim.x - 1);
    }
    __syncthreads();
    if (!is_last) return;
    if (threadIdx.x < 256) h[threadIdx.x] = atomicAdd(&bcnt[threadIdx.x], 0);
    __syncthreads();
    __shared__ int excl[256];
    if (threadIdx.x < 64) {
        int l = threadIdx.x;
        int v0 = h[4 * l], v1 = h[4 * l + 1], v2 = h[4 * l + 2], v3 = h[4 * l + 3];
        int tot = v0 + v1 + v2 + v3;
        int run = tot;
#pragma unroll
        for (int off = 1; off < 64; off <<= 1) {
            int t = __shfl_up(run, off);
            if (l >= off) run += t;
        }
        int ex = run - tot;
        excl[4 * l] = ex;
        excl[4 * l + 1] = ex + v0;
        excl[4 * l + 2] = ex + v0 + v1;
        excl[4 * l + 3] = ex + v0 + v1 + v2;
    }
    __syncthreads();
    if (threadIdx.x < nb) {
        int ex = excl[threadIdx.x];
        bstart[threadIdx.x] = ex;
        bcur[threadIdx.x] = ex;
        if (threadIdx.x == nb - 1) bstart[nb] = ex + h[threadIdx.x];
    }
}

// block-local counting sort by bucket, coalesced run flush.
// record: x = src | (dst&511)<<17 (src < 2^17), y = attr bits
__global__ __launch_bounds__(1024) void bin_kernel(
    const int* __restrict__ src, const int* __restrict__ dst, const float* __restrict__ eattr,
    int* __restrict__ bucket_cursor,
    int2* __restrict__ binned, int E, int nb)
{
    __shared__ int hist[256];
    __shared__ int basel[256];
    __shared__ int gbase[256];
    __shared__ int2 stage[4096];
    __shared__ unsigned char sb[4096];
    const int tid = threadIdx.x;
    const int e0 = blockIdx.x * 4096;
    const int valid = min(4096, E - e0);

    if (tid < 256) hist[tid] = 0;
    __syncthreads();

    int d[4], s[4], a[4], rk[4];
    bool ok[4];
    const int eb = e0 + tid * 4;
    if (eb + 3 < E) {
        int4 d4 = *(const int4*)(dst + eb);
        int4 s4 = *(const int4*)(src + eb);
        int4 a4 = *(const int4*)((const int*)eattr + eb);
        d[0] = d4.x; d[1] = d4.y; d[2] = d4.z; d[3] = d4.w;
        s[0] = s4.x; s[1] = s4.y; s[2] = s4.z; s[3] = s4.w;
        a[0] = a4.x; a[1] = a4.y; a[2] = a4.z; a[3] = a4.w;
        ok[0] = ok[1] = ok[2] = ok[3] = true;
    } else {
#pragma unroll
        for (int k = 0; k < 4; ++k) {
            int e = eb + k;
            ok[k] = e < E;
            if (ok[k]) {
                d[k] = dst[e];
                s[k] = src[e];
                a[k] = __float_as_int(eattr[e]);
            }
        }
    }
#pragma unroll
    for (int k = 0; k < 4; ++k) {
        if (ok[k]) rk[k] = atomicAdd(&hist[d[k] >> 9], 1);
    }
    __syncthreads();
    if (tid < 64) {
        int l = tid;
        int v0 = hist[4 * l], v1 = hist[4 * l + 1], v2 = hist[4 * l + 2], v3 = hist[4 * l + 3];
        int tot = v0 + v1 + v2 + v3;
        int run = tot;
#pragma unroll
        for (int off = 1; off < 64; off <<= 1) {
            int t = __shfl_up(run, off);
            if (l >= off) run += t;
        }
        int ex = run - tot;
        basel[4 * l] = ex;
        basel[4 * l + 1] = ex + v0;
        basel[4 * l + 2] = ex + v0 + v1;
        basel[4 * l + 3] = ex + v0 + v1 + v2;
    }
    __syncthreads();
    if (tid < nb && hist[tid] > 0) gbase[tid] = atomicAdd(&bucket_cursor[tid], hist[tid]);
#pragma unroll
    for (int k = 0; k < 4; ++k) {
        if (ok[k]) {
            int b = d[k] >> 9;
            int pos = basel[b] + rk[k];
            stage[pos] = make_int2(s[k] | ((d[k] & 511) << 17), a[k]);
            sb[pos] = (unsigned char)b;
        }
    }
    __syncthreads();
    for (int i = tid; i < valid; i += 1024) {
        int b = (int)sb[i];
        binned[gbase[b] + (i - basel[b])] = stage[i];
    }
}

// One block per bucket: LDS histogram by dlo -> rowptr slice -> cursor scatter
__global__ __launch_bounds__(1024) void fine_kernel(
    const int2* __restrict__ binned, const int* __restrict__ bstart,
    int* __restrict__ rowptr, int2* __restrict__ edges, int N, int nbuckets)
{
    __shared__ int hist[512];
    __shared__ int excl[512];
    const int tid = threadIdx.x;
    const int b = blockIdx.x;
    const int s0 = bstart[b], s1 = bstart[b + 1];
    if (tid < 512) hist[tid] = 0;
    __syncthreads();
    for (int i = s0 + tid; i < s1; i += 1024)
        atomicAdd(&hist[(binned[i].x >> 17) & 511], 1);
    __syncthreads();
    if (tid < 64) {
        int l = tid;
        int v[8], pre[8];
        int tot = 0;
#pragma unroll
        for (int k = 0; k < 8; ++k) { v[k] = hist[8 * l + k]; pre[k] = tot; tot += v[k]; }
        int run = tot;
#pragma unroll
        for (int off = 1; off < 64; off <<= 1) {
            int t = __shfl_up(run, off);
            if (l >= off) run += t;
        }
        int ex = run - tot;
#pragma unroll
        for (int k = 0; k < 8; ++k) excl[8 * l + k] = ex + pre[k];
    }
    __syncthreads();
    const int nbase = b << 9;
    if (tid < 512 && nbase + tid < N) rowptr[nbase + tid] = s0 + excl[tid];
    if (b == nbuckets - 1 && tid == 0) rowptr[N] = s1;
    __syncthreads();
    for (int i = s0 + tid; i < s1; i += 1024) {
        int2 ed = binned[i];
        int dlo = (ed.x >> 17) & 511;
        ed.x &= 0x1FFFF;
        int pos = atomicAdd(&excl[dlo], 1);
        edges[s0 + pos] = ed;
    }
}

// ---------------- pull aggregation (scalarized meta + packed f32x2 math) ----------------

__global__ __launch_bounds__(256) void pull1_kernel(
    const float* __restrict__ x,
    const int* __restrict__ rowptr, const int2* __restrict__ edges,
    const float* __restrict__ ne_w, const float* __restrict__ ne_b,
    const float* __restrict__ u1, const float* __restrict__ C1,
    u16* __restrict__ zb, int N)
{
    int lane = threadIdx.x & 63;
    int node = blockIdx.x * 4 + (threadIdx.x >> 6);
    if (node >= N) return;
    f32x2 A  = *(const f32x2*)(ne_w + 2 * lane);
    f32x2 Bv = *(const f32x2*)(u1   + 2 * lane);
    f32x2 Cv = *(const f32x2*)(C1   + 2 * lane);
    f32x2 nb = *(const f32x2*)(ne_b + 2 * lane);
    const f32x2 zero = {0.f, 0.f};
    int jb = rowptr[node], je = rowptr[node + 1];
    f32x2 acc = zero;
    int j = jb;
    for (; j + 8 <= je; j += 8) {
        float xs[8], av[8];
#pragma unroll
        for (int t = 0; t < 8; ++t) {
            int2 ep = edges[j + t];
            int s = __builtin_amdgcn_readfirstlane(ep.x);
            av[t] = __int_as_float(__builtin_amdgcn_readfirstlane(ep.y));
            xs[t] = x[s];
        }
#pragma unroll
        for (int t = 0; t < 8; ++t) {
            f32x2 m = __builtin_elementwise_fma((f32x2){xs[t], xs[t]}, A,
                        __builtin_elementwise_fma((f32x2){av[t], av[t]}, Bv, Cv));
            acc += __builtin_elementwise_max(m, zero);
        }
    }
    for (; j < je; ++j) {
        int2 ep = edges[j];
        int s = __builtin_amdgcn_readfirstlane(ep.x);
        float av = __int_as_float(__builtin_amdgcn_readfirstlane(ep.y));
        float xs = x[s];
        f32x2 m = __builtin_elementwise_fma((f32x2){xs, xs}, A,
                    __builtin_elementwise_fma((f32x2){av, av}, Bv, Cv));
        acc += __builtin_elementwise_max(m, zero);
    }
    float xn = x[node];
    f32x2 z = __builtin_elementwise_fma((f32x2){xn, xn}, A, nb) + acc;
    ((u32*)(zb + (long)node * 128))[lane] = (u32)f2bf(z.x) | ((u32)f2bf(z.y) << 16);
}

// pull2: one node per wave, 8-deep batches (measured-optimal operating point)
__global__ __launch_bounds__(256) void pull2_kernel(
    const u16* __restrict__ h1b,
    const int* __restrict__ rowptr, const int2* __restrict__ edges,
    const float* __restrict__ u2, const float* __restrict__ C2,
    u16* __restrict__ zb2, int N)
{
    int lane = threadIdx.x & 63;
    int node = blockIdx.x * 4 + (threadIdx.x >> 6);
    if (node >= N) return;
    f32x2 Bv = *(const f32x2*)(u2 + 2 * lane);
    f32x2 Cv = *(const f32x2*)(C2 + 2 * lane);
    const f32x2 zero = {0.f, 0.f};
    int jb = rowptr[node], je = rowptr[node + 1];
    f32x2 acc = zero;
    int j = jb;
    for (; j + 8 <= je; j += 8) {
        int sidx[8];
        float av[8];
        u32 hv[8];
#pragma unroll
        for (int t = 0; t < 8; ++t) {
            int2 ep = edges[j + t];
            sidx[t] = __builtin_amdgcn_readfirstlane(ep.x);
            av[t] = __int_as_float(__builtin_amdgcn_readfirstlane(ep.y));
        }
#pragma unroll
        for (int t = 0; t < 8; ++t)
            hv[t] = *(const u32*)(h1b + (long)sidx[t] * 128 + 2 * lane);
#pragma unroll
        for (int t = 0; t < 8; ++t) {
            f32x2 h = { __uint_as_float(hv[t] << 16), __uint_as_float(hv[t] & 0xFFFF0000u) };
            f32x2 m = h + __builtin_elementwise_fma((f32x2){av[t], av[t]}, Bv, Cv);
            acc += __builtin_elementwise_max(m, zero);
        }
    }
    for (; j < je; ++j) {
        int2 ep = edges[j];
        int s = __builtin_amdgcn_readfirstlane(ep.x);
        float av = __int_as_float(__builtin_amdgcn_readfirstlane(ep.y));
        u32 hv = *(const u32*)(h1b + (long)s * 128 + 2 * lane);
        f32x2 h = { __uint_as_float(hv << 16), __uint_as_float(hv & 0xFFFF0000u) };
        f32x2 m = h + __builtin_elementwise_fma((f32x2){av, av}, Bv, Cv);
        acc += __builtin_elementwise_max(m, zero);
    }
    u32 hn = *(const u32*)(h1b + (long)node * 128 + 2 * lane);
    f32x2 hnv = { __uint_as_float(hn << 16), __uint_as_float(hn & 0xFFFF0000u) };
    f32x2 z = hnv + acc;
    ((u32*)(zb2 + (long)node * 128))[lane] = (u32)f2bf(z.x) | ((u32)f2bf(z.y) << 16);
}

// ---------------- fused 2-GEMM node MLP (bf16 MFMA, split weights) ----------------
__global__ __launch_bounds__(256) void mlp_kernel(
    const u16* __restrict__ zb,
    const u16* __restrict__ w1hi, const u16* __restrict__ w1lo,
    const u16* __restrict__ w2hi, const u16* __restrict__ w2lo,
    const float* __restrict__ b1, const float* __restrict__ b2,
    u16* __restrict__ outb)
{
    __shared__ __align__(16) u16 tls[64][136];
    const int lane = threadIdx.x & 63;
    const int wv = threadIdx.x >> 6;
    const int m = lane & 15;
    const int q = lane >> 4;
    const int ko = q * 8;
    const long tile_row = (long)blockIdx.x * 64 + wv * 16;

    f32x4 acc[8];
#pragma unroll
    for (int ct = 0; ct < 8; ++ct) acc[ct] = (f32x4){0.f, 0.f, 0.f, 0.f};

#pragma unroll
    for (int ks = 0; ks < 4; ++ks) {
        bfrag a = *(const bfrag*)(zb + (tile_row + m) * 128 + ks * 32 + ko);
#pragma unroll
        for (int ct = 0; ct < 8; ++ct) {
            const int off = (((ks * 8 + ct) * 64) + lane) * 8;
            bfrag bh = *(const bfrag*)(w1hi + off);
            bfrag bl = *(const bfrag*)(w1lo + off);
            acc[ct] = __builtin_amdgcn_mfma_f32_16x16x32_bf16(a, bh, acc[ct], 0, 0, 0);
            acc[ct] = __builtin_amdgcn_mfma_f32_16x16x32_bf16(a, bl, acc[ct], 0, 0, 0);
        }
    }
#pragma unroll
    for (int ct = 0; ct < 8; ++ct) {
        float bv = b1[ct * 16 + m];
#pragma unroll
        for (int r = 0; r < 4; ++r) {
            float v = fmaxf(acc[ct][r] + bv, 0.f);
            tls[wv * 16 + q * 4 + r][ct * 16 + m] = f2bf(v);
        }
    }
    __syncthreads();

    f32x4 acc2[8];
#pragma unroll
    for (int ct = 0; ct < 8; ++ct) acc2[ct] = (f32x4){0.f, 0.f, 0.f, 0.f};

#pragma unroll
    for (int ks = 0; ks < 4; ++ks) {
        bfrag a = *(const bfrag*)(&tls[wv * 16 + m][ks * 32 + ko]);
#pragma unroll
        for (int ct = 0; ct < 8; ++ct) {
            const int off = (((ks * 8 + ct) * 64) + lane) * 8;
            bfrag bh = *(const bfrag*)(w2hi + off);
            bfrag bl = *(const bfrag*)(w2lo + off);
            acc2[ct] = __builtin_amdgcn_mfma_f32_16x16x32_bf16(a, bh, acc2[ct], 0, 0, 0);
            acc2[ct] = __builtin_amdgcn_mfma_f32_16x16x32_bf16(a, bl, acc2[ct], 0, 0, 0);
        }
    }
    __syncthreads();
#pragma unroll
    for (int ct = 0; ct < 8; ++ct) {
        float bv = b2[ct * 16 + m];
#pragma unroll
        for (int r = 0; r < 4; ++r) {
            float v = fmaxf(acc2[ct][r] + bv, 0.f);
            tls[wv * 16 + q * 4 + r][ct * 16 + m] = f2bf(v);
        }
    }
    __syncthreads();
    const long base_row = (long)blockIdx.x * 64;
#pragma unroll
    for (int it = 0; it < 4; ++it) {
        int chunk = threadIdx.x + it * 256;   // 0..1023
        int row = chunk >> 4;
        int c8 = (chunk & 15) * 8;
        *(uint4*)(outb + (base_row + row) * 128 + c8) = *(const uint4*)(&tls[row][c8]);
    }
}

// Same MLP but final layer: no h2 global write — pool directly from LDS.
__global__ __launch_bounds__(256) void mlp_pool_kernel(
    const u16* __restrict__ zb,
    const u16* __restrict__ w1hi, const u16* __restrict__ w1lo,
    const u16* __restrict__ w2hi, const u16* __restrict__ w2lo,
    const float* __restrict__ b1, const float* __restrict__ b2,
    const int* __restrict__ batch, float* __restrict__ poolacc, int N)
{
    __shared__ __align__(16) u16 tls[64][136];
    __shared__ int bsh[64];
    const int lane = threadIdx.x & 63;
    const int wv = threadIdx.x >> 6;
    const int m = lane & 15;
    const int q = lane >> 4;
    const int ko = q * 8;
    const long tile_row = (long)blockIdx.x * 64 + wv * 16;
    const long base_row = (long)blockIdx.x * 64;

    if (threadIdx.x < 64) {
        long node = base_row + threadIdx.x;
        bsh[threadIdx.x] = (node < N) ? batch[node] : -1;
    }

    f32x4 acc[8];
#pragma unroll
    for (int ct = 0; ct < 8; ++ct) acc[ct] = (f32x4){0.f, 0.f, 0.f, 0.f};

#pragma unroll
    for (int ks = 0; ks < 4; ++ks) {
        bfrag a = *(const bfrag*)(zb + (tile_row + m) * 128 + ks * 32 + ko);
#pragma unroll
        for (int ct = 0; ct < 8; ++ct) {
            const int off = (((ks * 8 + ct) * 64) + lane) * 8;
            bfrag bh = *(const bfrag*)(w1hi + off);
            bfrag bl = *(const bfrag*)(w1lo + off);
            acc[ct] = __builtin_amdgcn_mfma_f32_16x16x32_bf16(a, bh, acc[ct], 0, 0, 0);
            acc[ct] = __builtin_amdgcn_mfma_f32_16x16x32_bf16(a, bl, acc[ct], 0, 0, 0);
        }
    }
#pragma unroll
    for (int ct = 0; ct < 8; ++ct) {
        float bv = b1[ct * 16 + m];
#pragma unroll
        for (int r = 0; r < 4; ++r) {
            float v = fmaxf(acc[ct][r] + bv, 0.f);
            tls[wv * 16 + q * 4 + r][ct * 16 + m] = f2bf(v);
        }
    }
    __syncthreads();

    f32x4 acc2[8];
#pragma unroll
    for (int ct = 0; ct < 8; ++ct) acc2[ct] = (f32x4){0.f, 0.f, 0.f, 0.f};

#pragma unroll
    for (int ks = 0; ks < 4; ++ks) {
        bfrag a = *(const bfrag*)(&tls[wv * 16 + m][ks * 32 + ko]);
#pragma unroll
        for (int ct = 0; ct < 8; ++ct) {
            const int off = (((ks * 8 + ct) * 64) + lane) * 8;
            bfrag bh = *(const bfrag*)(w2hi + off);
            bfrag bl = *(const bfrag*)(w2lo + off);
            acc2[ct] = __builtin_amdgcn_mfma_f32_16x16x32_bf16(a, bh, acc2[ct], 0, 0, 0);
            acc2[ct] = __builtin_amdgcn_mfma_f32_16x16x32_bf16(a, bl, acc2[ct], 0, 0, 0);
        }
    }
    __syncthreads();   // tls reuse
#pragma unroll
    for (int ct = 0; ct < 8; ++ct) {
        float bv = b2[ct * 16 + m];
#pragma unroll
        for (int r = 0; r < 4; ++r) {
            float v = fmaxf(acc2[ct][r] + bv, 0.f);
            tls[wv * 16 + q * 4 + r][ct * 16 + m] = f2bf(v);
        }
    }
    __syncthreads();

    int c = threadIdx.x & 127;
    int half = threadIdx.x >> 7;
    int r0 = half * 32, r1 = r0 + 32;
    int cur = -1;
    float sum = 0.f;
    for (int r = r0; r < r1; ++r) {
        int g = bsh[r];
        if (g < 0) break;
        float v = bf2f((u32)tls[r][c]);
        if (g != cur) {
            if (cur >= 0) atomicAdd(&poolacc[cur * 128 + c], sum);
            sum = 0.f;
            cur = g;
        }
        sum += v;
    }
    if (cur >= 0) atomicAdd(&poolacc[cur * 128 + c], sum);
}

// divide by per-graph counts (binary search in sorted batch)
__global__ __launch_bounds__(128) void pool2_kernel(
    const float* __restrict__ acc, const int* __restrict__ batch,
    float* __restrict__ out, int n)
{
    int g = blockIdx.x;
    int c = threadIdx.x;
    int lo = 0, hi = n;
    while (lo < hi) { int mid = (lo + hi) >> 1; if (batch[mid] < g) lo = mid + 1; else hi = mid; }
    int s = lo;
    lo = s; hi = n;
    while (lo < hi) { int mid = (lo + hi) >> 1; if (batch[mid] < g + 1) lo = mid + 1; else hi = mid; }
    int cnt = lo - s;
    out[g * 128 + c] = acc[g * 128 + c] / (float)(cnt > 0 ? cnt : 1);
}

// ---------------- launch ----------------
extern "C" void kernel_launch(void* const* d_in, const int* in_sizes, int n_in,
                              void* d_out, int out_size, void* d_ws, size_t ws_size,
                              hipStream_t stream)
{
    const float* x      = (const float*)d_in[0];
    const int*   ei     = (const int*)d_in[1];
    const float* eattr  = (const float*)d_in[2];
    const int*   batch  = (const int*)d_in[3];
    const float* ne_w   = (const float*)d_in[4];
    const float* ne_b   = (const float*)d_in[5];
    const float* ee_w   = (const float*)d_in[6];
    const float* ee_b   = (const float*)d_in[7];
    const float* lin1_w = (const float*)d_in[8];
    const float* lin1_b = (const float*)d_in[9];
    const float* w11    = (const float*)d_in[10];
    const float* b11    = (const float*)d_in[11];
    const float* w12    = (const float*)d_in[12];
    const float* b12    = (const float*)d_in[13];
    const float* lin2_w = (const float*)d_in[14];
    const float* lin2_b = (const float*)d_in[15];
    const float* w21    = (const float*)d_in[16];
    const float* b21    = (const float*)d_in[17];
    const float* w22    = (const float*)d_in[18];
    const float* b22    = (const float*)d_in[19];

    const int N = in_sizes[0];
    const int E = in_sizes[2];
    const int G = out_size / 128;
    const int Npad = ((N + 63) / 64) * 64;
    const int nb = (N + 511) >> 9;     // 512-node buckets (<=256)
    const int* esrc = ei;
    const int* edst = ei + E;

    char* p = (char*)d_ws;
    auto alloc = [&](size_t bytes) -> void* {
        void* r = (void*)p;
        p += (bytes + 255) & ~(size_t)255;
        return r;
    };
    float* u1 = (float*)alloc(128 * 4);
    float* C1 = (float*)alloc(128 * 4);
    float* u2 = (float*)alloc(128 * 4);
    float* C2 = (float*)alloc(128 * 4);
    int* bcnt   = (int*)alloc(1024);
    int* done   = (int*)alloc(256);
    float* poolacc = (float*)alloc((size_t)G * 128 * 4);
    int* bstart = (int*)alloc(((size_t)nb + 1) * 4);
    int* bcur   = (int*)alloc((size_t)nb * 4);
    int* rowptr = (int*)alloc(((size_t)N + 1) * 4);
    int2* edges = (int2*)alloc((size_t)E * 8);
    int2* binned = (int2*)alloc((size_t)E * 8);
    u16* whi = (u16*)alloc((size_t)4 * 16384 * 2);
    u16* wlo = (u16*)alloc((size_t)4 * 16384 * 2);
    u16* bufA = (u16*)alloc((size_t)Npad * 128 * 2);
    u16* bufB = (u16*)alloc((size_t)Npad * 128 * 2);

    // one memset covers bcnt..done..poolacc (adjacent allocations)
    size_t zbytes = (size_t)((char*)poolacc + (size_t)G * 128 * 4 - (char*)bcnt);
    hipMemsetAsync(bcnt, 0, zbytes, stream);

    prepack_consts_kernel<<<257, 256, 0, stream>>>(
        w11, w12, w21, w22, whi, wlo,
        ne_b, ee_w, ee_b, lin1_w, lin1_b, lin2_w, lin2_b, u1, C1, u2, C2);

    bcount_kernel<<<(E + 4095) / 4096, 1024, 0, stream>>>(edst, bcnt, done, bstart, bcur, E, nb);
    bin_kernel<<<(E + 4095) / 4096, 1024, 0, stream>>>(esrc, edst, eattr, bcur, binned, E, nb);
    fine_kernel<<<nb, 1024, 0, stream>>>(binned, bstart, rowptr, edges, N, nb);

    pull1_kernel<<<(N + 3) / 4, 256, 0, stream>>>(x, rowptr, edges, ne_w, ne_b, u1, C1,
                                                  bufA, N);
    mlp_kernel<<<Npad / 64, 256, 0, stream>>>(bufA, whi, wlo, whi + 16384, wlo + 16384,
                                              b11, b12, bufB);
    pull2_kernel<<<(N + 3) / 4, 256, 0, stream>>>(bufB, rowptr, edges, u2, C2, bufA, N);
    mlp_pool_kernel<<<Npad / 64, 256, 0, stream>>>(bufA, whi + 32768, wlo + 32768,
                                                   whi + 49152, wlo + 49152, b21, b22,
                                                   batch, poolacc, N);

    pool2_kernel<<<G, 128, 0, stream>>>(poolacc, batch, (float*)d_out, N);
}